// Round 9
// baseline (201.050 us; speedup 1.0000x reference)
//
#include <hip/hip_runtime.h>
#include <cstdint>
#include <cstddef>

// Problem dims
#define BB 8
#define HH 512
#define PP 512
#define LL 2048

typedef __attribute__((ext_vector_type(8))) __bf16 bf16x8;
typedef __attribute__((ext_vector_type(4))) float f32x4;

__device__ __forceinline__ uint16_t f2bf(float f) {
  uint32_t u = __builtin_bit_cast(uint32_t, f);
  u += 0x7FFFu + ((u >> 16) & 1u);   // RNE
  return (uint16_t)(u >> 16);
}

__device__ __forceinline__ void async_copy16(const void* gptr, void* ldsptr) {
  __builtin_amdgcn_global_load_lds(
      (const __attribute__((address_space(1))) unsigned int*)gptr,
      (__attribute__((address_space(3))) unsigned int*)ldsptr,
      16, 0, 0);
}

// ---------------------------------------------------------------------------
// prep (A1/A2/Dd) + u transpose-convert fused into one launch.
// ---------------------------------------------------------------------------
__global__ __launch_bounds__(256) void prep_and_transpose(
    const float* __restrict__ U, const float* __restrict__ Bbar,
    const float* __restrict__ Cri, const float* __restrict__ Dm,
    uint16_t* __restrict__ Ut, uint16_t* __restrict__ A1,
    uint16_t* __restrict__ A2, float* __restrict__ Dd) {
  __shared__ uint16_t tile[64][66];
  const int t = threadIdx.x;
  if (blockIdx.x < 2048) {
    const int bid = blockIdx.x;
    const int b = bid >> 8;
    const int h0 = ((bid >> 5) & 7) * 64;
    const int l0 = (bid & 31) * 64;
    const int r = t >> 2, c = t & 3;
    const float* src = U + ((size_t)(b * 512 + h0 + r)) * 2048 + l0 + c * 16;
#pragma unroll
    for (int q = 0; q < 4; ++q) {
      float4 v = *(const float4*)(src + q * 4);
      *(uint32_t*)&tile[r][c * 16 + q * 4]     = (uint32_t)f2bf(v.x) | ((uint32_t)f2bf(v.y) << 16);
      *(uint32_t*)&tile[r][c * 16 + q * 4 + 2] = (uint32_t)f2bf(v.z) | ((uint32_t)f2bf(v.w) << 16);
    }
    __syncthreads();
    uint16_t* dst = Ut + ((size_t)(b * 2048 + l0 + r)) * 512 + h0 + c * 16;
    uint32_t o[8];
#pragma unroll
    for (int k = 0; k < 8; ++k)
      o[k] = (uint32_t)tile[c * 16 + 2 * k][r] | ((uint32_t)tile[c * 16 + 2 * k + 1][r] << 16);
    *(uint4*)(dst)     = make_uint4(o[0], o[1], o[2], o[3]);
    *(uint4*)(dst + 8) = make_uint4(o[4], o[5], o[6], o[7]);
  } else {
    int idx = (blockIdx.x - 2048) * 256 + t;   // 0 .. 512*512-1
    int p = idx >> 9, h = idx & 511;
    A1[(size_t)p * 512 + h]          = f2bf(Bbar[((size_t)p * 512 + h) * 2 + 0]);
    A1[(size_t)(512 + p) * 512 + h]  = f2bf(Bbar[((size_t)p * 512 + h) * 2 + 1]);
    int h2 = idx >> 9, p2 = idx & 511;
    A2[(size_t)h2 * 1024 + p2]        = f2bf( Cri[((size_t)h2 * 512 + p2) * 2 + 0]);
    A2[(size_t)h2 * 1024 + 512 + p2]  = f2bf(-Cri[((size_t)h2 * 512 + p2) * 2 + 1]);
    if (idx < 512) Dd[idx] = Dm[(size_t)idx * 512 + idx];
  }
}

// ---------------------------------------------------------------------------
// scan: in-place on Bu (B, 1024, 2048) bf16 (rows p = re, rows 512+p = im)
// ---------------------------------------------------------------------------
__global__ __launch_bounds__(256) void scan_kernel(
    const float* __restrict__ Lam, uint16_t* __restrict__ Bu) {
  const int gt = blockIdx.x * 256 + threadIdx.x;
  const int wave = gt >> 6, lane = gt & 63;
  const int b = wave >> 9, p = wave & 511;
  const float lr = Lam[p * 2 + 0], li = Lam[p * 2 + 1];
  float ar = lr, ai = li;
#pragma unroll
  for (int s = 0; s < 5; ++s) { float nr = ar * ar - ai * ai, ni = 2.f * ar * ai; ar = nr; ai = ni; }

  uint16_t* rowre = Bu + ((size_t)(b * 1024 + p)) * 2048 + lane * 32;
  uint16_t* rowim = Bu + ((size_t)(b * 1024 + 512 + p)) * 2048 + lane * 32;
  uint4 vr[4], vi[4];
#pragma unroll
  for (int q = 0; q < 4; ++q) { vr[q] = ((const uint4*)rowre)[q]; vi[q] = ((const uint4*)rowim)[q]; }

  float xr[32], xi[32];
  float sr = 0.f, si = 0.f;
#pragma unroll
  for (int q = 0; q < 4; ++q) {
    uint32_t wr[4] = {vr[q].x, vr[q].y, vr[q].z, vr[q].w};
    uint32_t wi[4] = {vi[q].x, vi[q].y, vi[q].z, vi[q].w};
#pragma unroll
    for (int d = 0; d < 4; ++d) {
      float br0 = __builtin_bit_cast(float, wr[d] << 16);
      float bi0 = __builtin_bit_cast(float, wi[d] << 16);
      float br1 = __builtin_bit_cast(float, wr[d] & 0xFFFF0000u);
      float bi1 = __builtin_bit_cast(float, wi[d] & 0xFFFF0000u);
      int j = q * 8 + d * 2;
      float nr = lr * sr - li * si + br0, ni = lr * si + li * sr + bi0;
      sr = nr; si = ni; xr[j] = sr; xi[j] = si;
      nr = lr * sr - li * si + br1; ni = lr * si + li * sr + bi1;
      sr = nr; si = ni; xr[j + 1] = sr; xi[j + 1] = si;
    }
  }
  float Ar = ar, Ai = ai, Sr = sr, Si = si;
#pragma unroll
  for (int off = 1; off < 64; off <<= 1) {
    float pAr = __shfl_up(Ar, off), pAi = __shfl_up(Ai, off);
    float pSr = __shfl_up(Sr, off), pSi = __shfl_up(Si, off);
    if (lane >= off) {
      float tSr = Ar * pSr - Ai * pSi + Sr;
      float tSi = Ar * pSi + Ai * pSr + Si;
      float tAr = Ar * pAr - Ai * pAi;
      float tAi = Ar * pAi + Ai * pAr;
      Sr = tSr; Si = tSi; Ar = tAr; Ai = tAi;
    }
  }
  float Cr = __shfl_up(Sr, 1), Ci = __shfl_up(Si, 1);
  if (lane == 0) { Cr = 0.f; Ci = 0.f; }
  float fr_ = lr * Cr - li * Ci, fi_ = lr * Ci + li * Cr;
#pragma unroll
  for (int j = 0; j < 32; ++j) {
    xr[j] += fr_; xi[j] += fi_;
    float nfr = fr_ * lr - fi_ * li, nfi = fr_ * li + fi_ * lr;
    fr_ = nfr; fi_ = nfi;
  }
#pragma unroll
  for (int q = 0; q < 4; ++q) {
    uint32_t wr[4], wi[4];
#pragma unroll
    for (int d = 0; d < 4; ++d) {
      int j = q * 8 + d * 2;
      wr[d] = (uint32_t)f2bf(xr[j]) | ((uint32_t)f2bf(xr[j + 1]) << 16);
      wi[d] = (uint32_t)f2bf(xi[j]) | ((uint32_t)f2bf(xi[j + 1]) << 16);
    }
    ((uint4*)rowre)[q] = make_uint4(wr[0], wr[1], wr[2], wr[3]);
    ((uint4*)rowim)[q] = make_uint4(wi[0], wi[1], wi[2], wi[3]);
  }
}

// ---------------------------------------------------------------------------
// transpose_x: x bf16 (b, 1024, 2048) -> Xt bf16 (b, 2048, 1024), 64x64 tiles
// ---------------------------------------------------------------------------
__global__ __launch_bounds__(256) void transpose_x(
    const uint16_t* __restrict__ X, uint16_t* __restrict__ Xt) {
  __shared__ uint16_t tile[64][66];
  const int t = threadIdx.x;
  const int b = blockIdx.z, p0 = blockIdx.y * 64, l0 = blockIdx.x * 64;
  const int r = t >> 2, c = t & 3;
  const uint16_t* src = X + ((size_t)(b * 1024 + p0 + r)) * 2048 + l0 + c * 16;
  uint4 v0 = *(const uint4*)(src);
  uint4 v1 = *(const uint4*)(src + 8);
  *(uint32_t*)&tile[r][c * 16 + 0]  = v0.x;
  *(uint32_t*)&tile[r][c * 16 + 2]  = v0.y;
  *(uint32_t*)&tile[r][c * 16 + 4]  = v0.z;
  *(uint32_t*)&tile[r][c * 16 + 6]  = v0.w;
  *(uint32_t*)&tile[r][c * 16 + 8]  = v1.x;
  *(uint32_t*)&tile[r][c * 16 + 10] = v1.y;
  *(uint32_t*)&tile[r][c * 16 + 12] = v1.z;
  *(uint32_t*)&tile[r][c * 16 + 14] = v1.w;
  __syncthreads();
  uint16_t* dst = Xt + ((size_t)(b * 2048 + l0 + r)) * 1024 + p0 + c * 16;
  uint32_t o[8];
#pragma unroll
  for (int k = 0; k < 8; ++k)
    o[k] = (uint32_t)tile[c * 16 + 2 * k][r] | ((uint32_t)tile[c * 16 + 2 * k + 1][r] << 16);
  *(uint4*)(dst)     = make_uint4(o[0], o[1], o[2], o[3]);
  *(uint4*)(dst + 8) = make_uint4(o[4], o[5], o[6], o[7]);
}

// ===========================================================================
// GEMMs: 64x64 tile, 128 threads = 2 waves (each 32m x 64n), BK=32,
// 2-buffer drain pipeline, 16 KiB LDS/block -> 8-10 blocks/CU (2x r8's 4):
// more independent barrier domains to overlap the per-iter staging latency
// (occupancy was the only lever that ever moved gemm2: r4->r5 49.6->44).
// Inner loop identical family to r7/r8: 6 ds_read_b128 + 8 MFMA per
// wave-iter, XOR chunk swizzle by ((row>>1)&3) (verified 0 conflicts).
// ===========================================================================
#define GEMM_CORE(KDIM)                                                       \
  constexpr int K = (KDIM), NT = K / 32;                                      \
  __shared__ __align__(16) uint16_t Alds[2][64 * 32];                         \
  __shared__ __align__(16) uint16_t Blds[2][64 * 32];                         \
  const int t = threadIdx.x, lane = t & 63, w = t >> 6;                       \
  const int m0 = blockIdx.y * 64, n0 = blockIdx.x * 64, b = blockIdx.z;       \
  /* staging: chunk ids id0=t, id1=t+128; row=id>>2, dest chunk=id&3,      */ \
  /* src chunk = (id&3)^((row>>1)&3)                                       */ \
  const int rA0 = t >> 2,         cA0 = (t & 3) ^ ((rA0 >> 1) & 3);           \
  const int id1 = t + 128;                                                    \
  const int rA1 = id1 >> 2,       cA1 = (id1 & 3) ^ ((rA1 >> 1) & 3);         \
  const uint16_t* pA0 = Amat + (size_t)(m0 + rA0) * K + cA0 * 8;              \
  const uint16_t* pA1 = Amat + (size_t)(m0 + rA1) * K + cA1 * 8;              \
  const uint16_t* pB0 = Bt + ((size_t)b * 2048 + n0 + rA0) * K + cA0 * 8;     \
  const uint16_t* pB1 = Bt + ((size_t)b * 2048 + n0 + rA1) * K + cA1 * 8;     \
  const int d0 = t * 8, d1 = id1 * 8;                                         \
  const int wm = w * 32;                                                      \
  const int fr = lane & 15, fq = lane >> 4;                                   \
  int offA[2], offB[4];                                                       \
  _Pragma("unroll")                                                           \
  for (int i = 0; i < 2; ++i) {                                               \
    int rm = wm + i * 16 + fr;                                                \
    offA[i] = rm * 32 + ((fq ^ ((rm >> 1) & 3)) * 8);                         \
  }                                                                           \
  _Pragma("unroll")                                                           \
  for (int j = 0; j < 4; ++j) {                                               \
    int rn = j * 16 + fr;                                                     \
    offB[j] = rn * 32 + ((fq ^ ((rn >> 1) & 3)) * 8);                         \
  }                                                                           \
  f32x4 acc[2][4];                                                            \
  _Pragma("unroll")                                                           \
  for (int i = 0; i < 2; ++i)                                                 \
    _Pragma("unroll")                                                         \
    for (int j = 0; j < 4; ++j) acc[i][j] = (f32x4){0.f, 0.f, 0.f, 0.f};      \
  /* prologue: tile 0 -> buf 0 */                                             \
  async_copy16(pA0, &Alds[0][d0]);                                            \
  async_copy16(pA1, &Alds[0][d1]);                                            \
  async_copy16(pB0, &Blds[0][d0]);                                            \
  async_copy16(pB1, &Blds[0][d1]);                                            \
  __syncthreads();                                                            \
  _Pragma("unroll 2")                                                         \
  for (int it = 0; it < NT; ++it) {                                           \
    const int cur = it & 1, nxt = cur ^ 1;                                    \
    if (it + 1 < NT) {                                                        \
      const int kb = (it + 1) * 32;                                           \
      async_copy16(pA0 + kb, &Alds[nxt][d0]);                                 \
      async_copy16(pA1 + kb, &Alds[nxt][d1]);                                 \
      async_copy16(pB0 + kb, &Blds[nxt][d0]);                                 \
      async_copy16(pB1 + kb, &Blds[nxt][d1]);                                 \
    }                                                                         \
    bf16x8 af[2], bv[4];                                                      \
    _Pragma("unroll")                                                         \
    for (int i = 0; i < 2; ++i) af[i] = *(const bf16x8*)&Alds[cur][offA[i]];  \
    _Pragma("unroll")                                                         \
    for (int j = 0; j < 4; ++j) bv[j] = *(const bf16x8*)&Blds[cur][offB[j]];  \
    _Pragma("unroll")                                                         \
    for (int i = 0; i < 2; ++i)                                               \
      _Pragma("unroll")                                                       \
      for (int j = 0; j < 4; ++j)                                             \
        acc[i][j] = __builtin_amdgcn_mfma_f32_16x16x32_bf16(af[i], bv[j], acc[i][j], 0, 0, 0); \
    __syncthreads();                                                          \
  }

// ---------------------------------------------------------------------------
// GEMM1: Bu[b,m,l] = sum_h A1[m,h]*Ut[b,l,h]. M=1024, N=2048/b, K=512
// ---------------------------------------------------------------------------
__global__ __launch_bounds__(128) void gemm1_fused(
    const uint16_t* __restrict__ Amat, const uint16_t* __restrict__ Bt,
    uint16_t* __restrict__ Bu) {
  GEMM_CORE(512)
  uint16_t* O = Bu + ((size_t)b * 1024 + m0) * 2048 + n0;
#pragma unroll
  for (int i = 0; i < 2; ++i)
#pragma unroll
    for (int j = 0; j < 4; ++j)
#pragma unroll
      for (int r = 0; r < 4; ++r) {
        int mm = wm + i * 16 + fq * 4 + r;
        int nn = j * 16 + fr;
        O[(size_t)mm * 2048 + nn] = f2bf(acc[i][j][r]);
      }
}

// ---------------------------------------------------------------------------
// GEMM2: out[b,h,l] = gelu(sum_k A2[h,k]*Xt[b,l,k] + Dd[h]*u[b,h,l])
// M=512, N=2048/b, K=1024
// ---------------------------------------------------------------------------
__global__ __launch_bounds__(128) void gemm2_fused(
    const uint16_t* __restrict__ Amat, const uint16_t* __restrict__ Bt,
    float* __restrict__ Out, const float* __restrict__ Dd,
    const float* __restrict__ Uu) {
  GEMM_CORE(1024)
  const size_t base = ((size_t)b * 512 + m0) * 2048 + n0;
  float* O = Out + base;
  const float* Ub = Uu + base;
#pragma unroll
  for (int i = 0; i < 2; ++i)
#pragma unroll
    for (int r = 0; r < 4; ++r) {
      int mm = wm + i * 16 + fq * 4 + r;
      float dv = Dd[m0 + mm];
#pragma unroll
      for (int j = 0; j < 4; ++j) {
        int nn = j * 16 + fr;
        float xv = acc[i][j][r] + dv * Ub[(size_t)mm * 2048 + nn];
        O[(size_t)mm * 2048 + nn] = 0.5f * xv * (1.f + erff(xv * 0.70710678118654752f));
      }
    }
}

// ---------------------------------------------------------------------------
extern "C" void kernel_launch(void* const* d_in, const int* in_sizes, int n_in,
                              void* d_out, int out_size, void* d_ws, size_t ws_size,
                              hipStream_t stream) {
  const float* u    = (const float*)d_in[0];   // (8,512,2048)
  const float* Lam  = (const float*)d_in[1];   // (512,2)
  const float* Bbar = (const float*)d_in[2];   // (512,512,2)
  const float* Cri  = (const float*)d_in[3];   // (512,512,2)
  const float* Dm   = (const float*)d_in[4];   // (512,512)
  float* out = (float*)d_out;

  char* ws = (char*)d_ws;
  uint16_t* Bu = (uint16_t*)(ws);                    // (8,1024,2048) bf16, 33.55 MB
  uint16_t* Xt = (uint16_t*)(ws + 33554432);         // (8,2048,1024) bf16, 33.55 MB
  uint16_t* Ut = (uint16_t*)(ws + 33554432);         // (8,2048,512) bf16 — aliases Xt,
                                                     // dead before transpose_x runs
  uint16_t* A1 = (uint16_t*)(ws + 67108864);         // (1024,512) bf16, 1 MB
  uint16_t* A2 = (uint16_t*)(ws + 68157440);         // (512,1024) bf16, 1 MB
  float*    Dd = (float*)   (ws + 69206016);         // (512) f32

  prep_and_transpose<<<3072, 256, 0, stream>>>(u, Bbar, Cri, Dm, Ut, A1, A2, Dd);
  gemm1_fused<<<dim3(32, 16, BB), 128, 0, stream>>>(A1, Ut, Bu);
  scan_kernel<<<1024, 256, 0, stream>>>(Lam, Bu);
  transpose_x<<<dim3(32, 16, BB), 256, 0, stream>>>(Bu, Xt);
  gemm2_fused<<<dim3(32, 8, BB), 128, 0, stream>>>(A2, Xt, out, Dd, u);
}

// Round 10
// 172.827 us; speedup vs baseline: 1.1633x; 1.1633x over previous
//
#include <hip/hip_runtime.h>
#include <cstdint>
#include <cstddef>

// Problem dims
#define BB 8
#define HH 512
#define PP 512
#define LL 2048

typedef __attribute__((ext_vector_type(8))) __bf16 bf16x8;
typedef __attribute__((ext_vector_type(4))) float f32x4;

__device__ __forceinline__ uint16_t f2bf(float f) {
  uint32_t u = __builtin_bit_cast(uint32_t, f);
  u += 0x7FFFu + ((u >> 16) & 1u);   // RNE
  return (uint16_t)(u >> 16);
}

__device__ __forceinline__ void async_copy16(const void* gptr, void* ldsptr) {
  __builtin_amdgcn_global_load_lds(
      (const __attribute__((address_space(1))) unsigned int*)gptr,
      (__attribute__((address_space(3))) unsigned int*)ldsptr,
      16, 0, 0);
}

// ---------------------------------------------------------------------------
// prep (A1/A2/Dd) + u transpose-convert fused into one launch.
// ---------------------------------------------------------------------------
__global__ __launch_bounds__(256) void prep_and_transpose(
    const float* __restrict__ U, const float* __restrict__ Bbar,
    const float* __restrict__ Cri, const float* __restrict__ Dm,
    uint16_t* __restrict__ Ut, uint16_t* __restrict__ A1,
    uint16_t* __restrict__ A2, float* __restrict__ Dd) {
  __shared__ uint16_t tile[64][66];
  const int t = threadIdx.x;
  if (blockIdx.x < 2048) {
    const int bid = blockIdx.x;
    const int b = bid >> 8;
    const int h0 = ((bid >> 5) & 7) * 64;
    const int l0 = (bid & 31) * 64;
    const int r = t >> 2, c = t & 3;
    const float* src = U + ((size_t)(b * 512 + h0 + r)) * 2048 + l0 + c * 16;
#pragma unroll
    for (int q = 0; q < 4; ++q) {
      float4 v = *(const float4*)(src + q * 4);
      *(uint32_t*)&tile[r][c * 16 + q * 4]     = (uint32_t)f2bf(v.x) | ((uint32_t)f2bf(v.y) << 16);
      *(uint32_t*)&tile[r][c * 16 + q * 4 + 2] = (uint32_t)f2bf(v.z) | ((uint32_t)f2bf(v.w) << 16);
    }
    __syncthreads();
    uint16_t* dst = Ut + ((size_t)(b * 2048 + l0 + r)) * 512 + h0 + c * 16;
    uint32_t o[8];
#pragma unroll
    for (int k = 0; k < 8; ++k)
      o[k] = (uint32_t)tile[c * 16 + 2 * k][r] | ((uint32_t)tile[c * 16 + 2 * k + 1][r] << 16);
    *(uint4*)(dst)     = make_uint4(o[0], o[1], o[2], o[3]);
    *(uint4*)(dst + 8) = make_uint4(o[4], o[5], o[6], o[7]);
  } else {
    int idx = (blockIdx.x - 2048) * 256 + t;   // 0 .. 512*512-1
    int p = idx >> 9, h = idx & 511;
    A1[(size_t)p * 512 + h]          = f2bf(Bbar[((size_t)p * 512 + h) * 2 + 0]);
    A1[(size_t)(512 + p) * 512 + h]  = f2bf(Bbar[((size_t)p * 512 + h) * 2 + 1]);
    int h2 = idx >> 9, p2 = idx & 511;
    A2[(size_t)h2 * 1024 + p2]        = f2bf( Cri[((size_t)h2 * 512 + p2) * 2 + 0]);
    A2[(size_t)h2 * 1024 + 512 + p2]  = f2bf(-Cri[((size_t)h2 * 512 + p2) * 2 + 1]);
    if (idx < 512) Dd[idx] = Dm[(size_t)idx * 512 + idx];
  }
}

// ---------------------------------------------------------------------------
// scan_tr: scan Bu (B,1024,2048) along l AND write transposed-grouped output
// Xt8[b][g][l][8] (g = k>>3, k = [re p 0..511; im 512..1023]) in one pass.
// Block = 512 threads = 8 waves = the 8 complex chains (p0..p0+7) of one
// k-group; per-wave scan identical to the verified scan_kernel. Results go
// через 64KB LDS (chain-major rows, uint4 writes) then coalesced 16B stores.
// Replaces scan_kernel + transpose_x (saves 67MB traffic + one launch).
// ---------------------------------------------------------------------------
__global__ __launch_bounds__(512) void scan_tr(
    const float* __restrict__ Lam, const uint16_t* __restrict__ Bu,
    uint16_t* __restrict__ Xt8) {
  __shared__ uint16_t S[16][2048];   // [wave*2 + (0=re,1=im)][l], 64 KiB
  const int t = threadIdx.x, wave = t >> 6, lane = t & 63;
  const int b = blockIdx.x >> 6, p0 = (blockIdx.x & 63) * 8, p = p0 + wave;

  const float lr = Lam[p * 2 + 0], li = Lam[p * 2 + 1];
  float ar = lr, ai = li;
#pragma unroll
  for (int s = 0; s < 5; ++s) { float nr = ar * ar - ai * ai, ni = 2.f * ar * ai; ar = nr; ai = ni; }

  const uint16_t* rowre = Bu + ((size_t)(b * 1024 + p)) * 2048 + lane * 32;
  const uint16_t* rowim = Bu + ((size_t)(b * 1024 + 512 + p)) * 2048 + lane * 32;
  uint4 vr[4], vi[4];
#pragma unroll
  for (int q = 0; q < 4; ++q) { vr[q] = ((const uint4*)rowre)[q]; vi[q] = ((const uint4*)rowim)[q]; }

  float xr[32], xi[32];
  float sr = 0.f, si = 0.f;
#pragma unroll
  for (int q = 0; q < 4; ++q) {
    uint32_t wr[4] = {vr[q].x, vr[q].y, vr[q].z, vr[q].w};
    uint32_t wi[4] = {vi[q].x, vi[q].y, vi[q].z, vi[q].w};
#pragma unroll
    for (int d = 0; d < 4; ++d) {
      float br0 = __builtin_bit_cast(float, wr[d] << 16);
      float bi0 = __builtin_bit_cast(float, wi[d] << 16);
      float br1 = __builtin_bit_cast(float, wr[d] & 0xFFFF0000u);
      float bi1 = __builtin_bit_cast(float, wi[d] & 0xFFFF0000u);
      int j = q * 8 + d * 2;
      float nr = lr * sr - li * si + br0, ni = lr * si + li * sr + bi0;
      sr = nr; si = ni; xr[j] = sr; xi[j] = si;
      nr = lr * sr - li * si + br1; ni = lr * si + li * sr + bi1;
      sr = nr; si = ni; xr[j + 1] = sr; xi[j + 1] = si;
    }
  }
  float Ar = ar, Ai = ai, Sr = sr, Si = si;
#pragma unroll
  for (int off = 1; off < 64; off <<= 1) {
    float pAr = __shfl_up(Ar, off), pAi = __shfl_up(Ai, off);
    float pSr = __shfl_up(Sr, off), pSi = __shfl_up(Si, off);
    if (lane >= off) {
      float tSr = Ar * pSr - Ai * pSi + Sr;
      float tSi = Ar * pSi + Ai * pSr + Si;
      float tAr = Ar * pAr - Ai * pAi;
      float tAi = Ar * pAi + Ai * pAr;
      Sr = tSr; Si = tSi; Ar = tAr; Ai = tAi;
    }
  }
  float Cr = __shfl_up(Sr, 1), Ci = __shfl_up(Si, 1);
  if (lane == 0) { Cr = 0.f; Ci = 0.f; }
  float fr_ = lr * Cr - li * Ci, fi_ = lr * Ci + li * Cr;
#pragma unroll
  for (int j = 0; j < 32; ++j) {
    xr[j] += fr_; xi[j] += fi_;
    float nfr = fr_ * lr - fi_ * li, nfi = fr_ * li + fi_ * lr;
    fr_ = nfr; fi_ = nfi;
  }
  // stage scanned values into LDS (chain-major; uint4 stores)
#pragma unroll
  for (int q = 0; q < 4; ++q) {
    uint32_t wr[4], wi[4];
#pragma unroll
    for (int d = 0; d < 4; ++d) {
      int j = q * 8 + d * 2;
      wr[d] = (uint32_t)f2bf(xr[j]) | ((uint32_t)f2bf(xr[j + 1]) << 16);
      wi[d] = (uint32_t)f2bf(xi[j]) | ((uint32_t)f2bf(xi[j + 1]) << 16);
    }
    *(uint4*)&S[wave * 2 + 0][lane * 32 + q * 8] = make_uint4(wr[0], wr[1], wr[2], wr[3]);
    *(uint4*)&S[wave * 2 + 1][lane * 32 + q * 8] = make_uint4(wi[0], wi[1], wi[2], wi[3]);
  }
  __syncthreads();
  // write-out: group g = b*128 + c*64 + (p0>>3); Xt8[(g*2048 + l)*8 + w]
  const size_t gre = (size_t)b * 128 + (p0 >> 3);
#pragma unroll
  for (int c = 0; c < 2; ++c) {
    uint16_t* dst = Xt8 + (gre + (size_t)c * 64) * 2048 * 8;
#pragma unroll
    for (int rep = 0; rep < 4; ++rep) {
      int l = rep * 512 + t;
      uint32_t o0 = (uint32_t)S[0 + c][l] | ((uint32_t)S[2 + c][l] << 16);
      uint32_t o1 = (uint32_t)S[4 + c][l] | ((uint32_t)S[6 + c][l] << 16);
      uint32_t o2 = (uint32_t)S[8 + c][l] | ((uint32_t)S[10 + c][l] << 16);
      uint32_t o3 = (uint32_t)S[12 + c][l] | ((uint32_t)S[14 + c][l] << 16);
      *(uint4*)(dst + (size_t)l * 8) = make_uint4(o0, o1, o2, o3);
    }
  }
}

// ===========================================================================
// GEMMs: r8-frozen structure (best measured): BM=128, BN=64, BK=32, 4 waves,
// 3 LDS buffers (36 KiB), 2-deep prefetch, counted vmcnt(3), XOR chunk
// swizzle by ((row>>1)&3) (verified 0 bank conflicts). Parameterized on the
// B-operand source address (PB0) and per-K-tile source stride (BSTRIDE).
// ===========================================================================
#define GEMM_CORE(KDIM, PB0_EXPR, BSTRIDE)                                    \
  constexpr int K = (KDIM), NT = K / 32;                                      \
  __shared__ __align__(16) uint16_t Alds[3][128 * 32];                        \
  __shared__ __align__(16) uint16_t Blds[3][64 * 32];                         \
  const int t = threadIdx.x, lane = t & 63, w = t >> 6;                       \
  const int m0 = blockIdx.y * 128, n0 = blockIdx.x * 64, b = blockIdx.z;      \
  const int r0 = t >> 2;                                                      \
  const int c0 = (t & 3) ^ ((r0 >> 1) & 3);                                   \
  const uint16_t* pA0 = Amat + (size_t)(m0 + r0) * K + c0 * 8;                \
  const uint16_t* pA1 = Amat + (size_t)(m0 + 64 + r0) * K + c0 * 8;           \
  const uint16_t* pB0 = (PB0_EXPR);                                           \
  const int d0 = t * 8;                                                       \
  const int wm = (w >> 1) * 64, wn = (w & 1) * 32;                            \
  const int fr = lane & 15, fq = lane >> 4;                                   \
  int offA[4], offB[2];                                                       \
  _Pragma("unroll")                                                           \
  for (int i = 0; i < 4; ++i) {                                               \
    int rm = wm + i * 16 + fr;                                                \
    offA[i] = rm * 32 + ((fq ^ ((rm >> 1) & 3)) * 8);                         \
  }                                                                           \
  _Pragma("unroll")                                                           \
  for (int j = 0; j < 2; ++j) {                                               \
    int rn = wn + j * 16 + fr;                                                \
    offB[j] = rn * 32 + ((fq ^ ((rn >> 1) & 3)) * 8);                         \
  }                                                                           \
  f32x4 acc[4][2];                                                            \
  _Pragma("unroll")                                                           \
  for (int i = 0; i < 4; ++i)                                                 \
    _Pragma("unroll")                                                         \
    for (int j = 0; j < 2; ++j) acc[i][j] = (f32x4){0.f, 0.f, 0.f, 0.f};      \
  /* prologue: tile 0 -> buf0, tile 1 -> buf1 (6 loads in flight) */          \
  async_copy16(pA0,             &Alds[0][d0]);                                \
  async_copy16(pA1,             &Alds[0][2048 + d0]);                         \
  async_copy16(pB0,             &Blds[0][d0]);                                \
  async_copy16(pA0 + 32,        &Alds[1][d0]);                                \
  async_copy16(pA1 + 32,        &Alds[1][2048 + d0]);                         \
  async_copy16(pB0 + (BSTRIDE), &Blds[1][d0]);                                \
  _Pragma("unroll")                                                           \
  for (int kt = 0; kt < NT; ++kt) {                                           \
    const int cur = kt % 3;                                                   \
    if (kt + 1 < NT) asm volatile("s_waitcnt vmcnt(3)" ::: "memory");         \
    else             asm volatile("s_waitcnt vmcnt(0)" ::: "memory");         \
    __builtin_amdgcn_s_barrier();                                             \
    __builtin_amdgcn_sched_barrier(0);                                        \
    if (kt + 2 < NT) {                                                        \
      const int nb = (kt + 2) % 3;                                            \
      const int kb = (kt + 2) * 32;                                           \
      async_copy16(pA0 + kb, &Alds[nb][d0]);                                  \
      async_copy16(pA1 + kb, &Alds[nb][2048 + d0]);                           \
      async_copy16(pB0 + (size_t)(kt + 2) * (BSTRIDE), &Blds[nb][d0]);        \
    }                                                                         \
    bf16x8 af[4], bv[2];                                                      \
    _Pragma("unroll")                                                         \
    for (int i = 0; i < 4; ++i) af[i] = *(const bf16x8*)&Alds[cur][offA[i]];  \
    _Pragma("unroll")                                                         \
    for (int j = 0; j < 2; ++j) bv[j] = *(const bf16x8*)&Blds[cur][offB[j]];  \
    _Pragma("unroll")                                                         \
    for (int i = 0; i < 4; ++i)                                               \
      _Pragma("unroll")                                                       \
      for (int j = 0; j < 2; ++j)                                             \
        acc[i][j] = __builtin_amdgcn_mfma_f32_16x16x32_bf16(af[i], bv[j], acc[i][j], 0, 0, 0); \
  }

// ---------------------------------------------------------------------------
// GEMM1: Bu[b,m,l] = sum_h A1[m,h]*Ut[b,l,h]. M=1024, N=2048/b, K=512
// ---------------------------------------------------------------------------
__global__ __launch_bounds__(256) void gemm1_fused(
    const uint16_t* __restrict__ Amat, const uint16_t* __restrict__ Bt,
    uint16_t* __restrict__ Bu) {
  GEMM_CORE(512, Bt + ((size_t)b * 2048 + n0 + r0) * 512 + c0 * 8, 32)
  uint16_t* O = Bu + ((size_t)b * 1024 + m0) * 2048 + n0;
#pragma unroll
  for (int i = 0; i < 4; ++i)
#pragma unroll
    for (int j = 0; j < 2; ++j)
#pragma unroll
      for (int r = 0; r < 4; ++r) {
        int mm = wm + i * 16 + fq * 4 + r;
        int nn = wn + j * 16 + fr;
        O[(size_t)mm * 2048 + nn] = f2bf(acc[i][j][r]);
      }
}

// ---------------------------------------------------------------------------
// GEMM2: out[b,h,l] = gelu(sum_k A2[h,k]*x[b,k,l] + Dd[h]*u[b,h,l])
// M=512, N=2048/b, K=1024; B operand read from Xt8[b][g][l][8] (g=k>>3):
// chunk c0 of K-tile kt at row l=n0+r0 lives at ((b*128+kt*4+c0)*2048+l)*8.
// ---------------------------------------------------------------------------
__global__ __launch_bounds__(256) void gemm2_fused(
    const uint16_t* __restrict__ Amat, const uint16_t* __restrict__ Bt,
    float* __restrict__ Out, const float* __restrict__ Dd,
    const float* __restrict__ Uu) {
  GEMM_CORE(1024, Bt + (((size_t)b * 128 + c0) * 2048 + n0 + r0) * 8, 65536)
  const size_t base = ((size_t)b * 512 + m0) * 2048 + n0;
  float* O = Out + base;
  const float* Ub = Uu + base;
#pragma unroll
  for (int i = 0; i < 4; ++i)
#pragma unroll
    for (int r = 0; r < 4; ++r) {
      int mm = wm + i * 16 + fq * 4 + r;
      float dv = Dd[m0 + mm];
#pragma unroll
      for (int j = 0; j < 2; ++j) {
        int nn = wn + j * 16 + fr;
        float xv = acc[i][j][r] + dv * Ub[(size_t)mm * 2048 + nn];
        O[(size_t)mm * 2048 + nn] = 0.5f * xv * (1.f + erff(xv * 0.70710678118654752f));
      }
    }
}

// ---------------------------------------------------------------------------
extern "C" void kernel_launch(void* const* d_in, const int* in_sizes, int n_in,
                              void* d_out, int out_size, void* d_ws, size_t ws_size,
                              hipStream_t stream) {
  const float* u    = (const float*)d_in[0];   // (8,512,2048)
  const float* Lam  = (const float*)d_in[1];   // (512,2)
  const float* Bbar = (const float*)d_in[2];   // (512,512,2)
  const float* Cri  = (const float*)d_in[3];   // (512,512,2)
  const float* Dm   = (const float*)d_in[4];   // (512,512)
  float* out = (float*)d_out;

  char* ws = (char*)d_ws;
  uint16_t* Bu  = (uint16_t*)(ws);                   // (8,1024,2048) bf16, 33.55 MB
  uint16_t* Xt8 = (uint16_t*)(ws + 33554432);        // (8,128,2048,8) bf16, 33.55 MB
  uint16_t* Ut  = (uint16_t*)(ws + 33554432);        // (8,2048,512) bf16 — aliases Xt8,
                                                     // dead before scan_tr runs
  uint16_t* A1 = (uint16_t*)(ws + 67108864);         // (1024,512) bf16, 1 MB
  uint16_t* A2 = (uint16_t*)(ws + 68157440);         // (512,1024) bf16, 1 MB
  float*    Dd = (float*)   (ws + 69206016);         // (512) f32

  prep_and_transpose<<<3072, 256, 0, stream>>>(u, Bbar, Cri, Dm, Ut, A1, A2, Dd);
  gemm1_fused<<<dim3(32, 8, BB), 256, 0, stream>>>(A1, Ut, Bu);
  scan_tr<<<512, 512, 0, stream>>>(Lam, Bu, Xt8);
  gemm2_fused<<<dim3(32, 4, BB), 256, 0, stream>>>(A2, Xt8, out, Dd, u);
}